// Round 3
// baseline (101.690 us; speedup 1.0000x reference)
//
#include <hip/hip_runtime.h>
#include <math.h>

// Match numpy f32 semantics bit-exactly: NO FMA contraction anywhere.
#pragma clang fp contract(off)

#define B_      2
#define L_      2048
#define K_      32
#define NBINS   37
#define H_      64
#define WD_ROWS 925   // 5*5*37
#define ITEMS   32    // items (b,l,k) per block

// Correctly-rounded f32 sqrt (Figueroa: f64 sqrt then round == RN f32 sqrt).
__device__ __forceinline__ float sqrt_f32_exact(float s) {
  return (float)sqrt((double)s);
}

// v / max(||v||, 1e-12) in f32, numpy op order: ((x*x + y*y) + z*z)
__device__ __forceinline__ void norm3f(float& x, float& y, float& z) {
  float s = (x*x + y*y) + z*z;
  float n = sqrt_f32_exact(s);
  n = fmaxf(n, 1e-12f);
  x = x / n; y = y / n; z = z / n;
}

// peW[rel+32][h] = b_edge[h] + sum_j pe_j(rel) * W_pe[j][h]   (65 x 64, f32)
// f64 internals: PE term is continuous; ~1e-6 abs error vs numpy f32 is fine.
__global__ void pew_kernel(const float* __restrict__ W_edge,
                           const float* __restrict__ b_edge,
                           float* __restrict__ peW) {
  __shared__ double pe[64];
  const int r = blockIdx.x;     // rel+32 in [0,64]
  const int h = threadIdx.x;    // 0..63
  if (h < 32) {
    const double c = -log(10000.0) / 64.0;
    const double ang = (double)(r - 32) * exp((double)(2 * h) * c);
    pe[2*h]     = sin(ang);
    pe[2*h + 1] = cos(ang);
  }
  __syncthreads();
  double acc = (double)b_edge[h];
  for (int j = 0; j < 64; ++j)
    acc += pe[j] * (double)W_edge[(WD_ROWS + j) * H_ + h];
  peW[r * H_ + h] = (float)acc;
}

__global__ __launch_bounds__(256) void edge_kernel(
    const float* __restrict__ coords,   // (B,L,4,3) f32
    const int*   __restrict__ nbr,      // (B,L,K) int32
    const float* __restrict__ W_edge,   // (989,64) f32
    const float* __restrict__ peW,      // (65,64) f32
    float*       __restrict__ out)      // (B,L,K,64) f32
{
  __shared__ float          atoms[2 * ITEMS][5][3];  // slot 2i = center(l), 2i+1 = neighbor(j)
  __shared__ unsigned short fidx[ITEMS][25];         // p*37 + bin
  __shared__ int            relid[ITEMS];            // rel+32 in [0,64]

  const int t  = threadIdx.x;
  const int g0 = blockIdx.x * ITEMS;

  // ---- Phase A0: per-residue atoms + virtual CB (f32, numpy-order, no FMA) ----
  if (t < 2 * ITEMS) {
    const int i  = t >> 1;
    const int g  = g0 + i;
    const int b  = g / (L_ * K_);
    const int lk = g - b * (L_ * K_);
    const int l  = lk / K_;
    const int nb = nbr[g];
    const int res = (t & 1) ? nb : l;
    const float* cp = coords + (size_t)(b * L_ + res) * 12;
    float a[4][3];
    #pragma unroll
    for (int q = 0; q < 4; ++q)
      #pragma unroll
      for (int d = 0; d < 3; ++d)
        a[q][d] = cp[q * 3 + d];

    // ca_n = normalize(N - CA); ca_c = normalize(C - CA)
    float nx = a[0][0]-a[1][0], ny = a[0][1]-a[1][1], nz = a[0][2]-a[1][2];
    float cx = a[2][0]-a[1][0], cy = a[2][1]-a[1][1], cz = a[2][2]-a[1][2];
    norm3f(nx, ny, nz);
    norm3f(cx, cy, cz);
    // bisector = normalize(ca_n + ca_c)
    float bx = nx + cx, by = ny + cy, bz = nz + cz;
    norm3f(bx, by, bz);
    // perpendicular = normalize(cross(ca_n, ca_c))  (mul, mul, sub — no FMA)
    float px = ny*cz - nz*cy, py = nz*cx - nx*cz, pz = nx*cy - ny*cx;
    norm3f(px, py, pz);
    // cb_dir = normalize(-bisector + 0.5*perpendicular)
    float dx = -bx + 0.5f*px, dy = -by + 0.5f*py, dz = -bz + 0.5f*pz;
    norm3f(dx, dy, dz);

    #pragma unroll
    for (int q = 0; q < 4; ++q)
      #pragma unroll
      for (int d = 0; d < 3; ++d)
        atoms[t][q][d] = a[q][d];
    // virtual_cb = CA + 1.54 * cb_dir   (f32 mul then add)
    atoms[t][4][0] = a[1][0] + 1.54f * dx;
    atoms[t][4][1] = a[1][1] + 1.54f * dy;
    atoms[t][4][2] = a[1][2] + 1.54f * dz;

    if ((t & 1) == 0) {
      int rel = nb - l;
      rel = rel < -32 ? -32 : (rel > 32 ? 32 : rel);
      relid[i] = rel + 32;
    }
  }
  __syncthreads();

  // ---- Phase A: 25 pair distances per item -> exact f32 searchsorted ----
  for (int task = t; task < ITEMS * 25; task += 256) {
    const int i  = task / 25;
    const int p  = task - i * 25;
    const int a1 = p / 5, a2 = p - a1 * 5;
    const float dx = atoms[2*i][a1][0] - atoms[2*i + 1][a2][0];
    const float dy = atoms[2*i][a1][1] - atoms[2*i + 1][a2][1];
    const float dz = atoms[2*i][a1][2] - atoms[2*i + 1][a2][2];
    const float d2 = (dx*dx + dy*dy) + dz*dz;   // numpy add.reduce order
    const float d  = sqrt_f32_exact(d2);        // correctly-rounded f32 sqrt
    // m = #{ bins[i] < d }, bins[i] = 2 + 0.5*i exactly representable in f32
    int m = (int)ceilf((d - 2.0f) * 2.0f);      // seed; fixups make it exact
    if (m < 0)  m = 0;
    if (m > NBINS) m = NBINS;
    while (m < NBINS && (2.0f + 0.5f * (float)m) < d) ++m;
    while (m > 0 && !((2.0f + 0.5f * (float)(m - 1)) < d)) --m;
    const int idx = m < (NBINS - 1) ? m : (NBINS - 1);   // clip
    fidx[i][p] = (unsigned short)(p * NBINS + idx);
  }
  __syncthreads();

  // ---- Phase B: out[g][h] = peW[rel] + sum_p W_dist[fidx[p]]  (8 h per thread) ----
  {
    const int i  = t >> 3;
    const int hq = (t & 7) * 8;
    const int g  = g0 + i;

    const float4* pw = (const float4*)(peW + relid[i] * H_ + hq);
    const float4 p0 = pw[0], p1 = pw[1];
    float acc[8] = {p0.x, p0.y, p0.z, p0.w, p1.x, p1.y, p1.z, p1.w};

    #pragma unroll 5
    for (int p = 0; p < 25; ++p) {
      const int f = fidx[i][p];
      const float4* wr = (const float4*)(W_edge + (size_t)f * H_ + hq);
      const float4 w0 = wr[0], w1 = wr[1];
      acc[0] += w0.x; acc[1] += w0.y; acc[2] += w0.z; acc[3] += w0.w;
      acc[4] += w1.x; acc[5] += w1.y; acc[6] += w1.z; acc[7] += w1.w;
    }

    float4* po = (float4*)(out + (size_t)g * H_ + hq);
    po[0] = make_float4(acc[0], acc[1], acc[2], acc[3]);
    po[1] = make_float4(acc[4], acc[5], acc[6], acc[7]);
  }
}

extern "C" void kernel_launch(void* const* d_in, const int* in_sizes, int n_in,
                              void* d_out, int out_size, void* d_ws, size_t ws_size,
                              hipStream_t stream) {
  const float* coords = (const float*)d_in[0];
  const int*   nbr    = (const int*)d_in[1];
  const float* W      = (const float*)d_in[2];
  const float* bvec   = (const float*)d_in[3];
  float*       out    = (float*)d_out;
  float*       peW    = (float*)d_ws;   // 65*64*4 = 16640 B scratch

  pew_kernel<<<65, 64, 0, stream>>>(W, bvec, peW);
  edge_kernel<<<(B_ * L_ * K_) / ITEMS, 256, 0, stream>>>(coords, nbr, W, peW, out);
}

// Round 4
// 100.889 us; speedup vs baseline: 1.0079x; 1.0079x over previous
//
#include <hip/hip_runtime.h>
#include <math.h>

// Match numpy f32 semantics bit-exactly: NO FMA contraction anywhere.
#pragma clang fp contract(off)

#define B_      2
#define L_      2048
#define K_      32
#define NBINS   37
#define H_      64
#define WD_ROWS 925   // 5*5*37
#define NRES    (B_ * L_)

// Correctly-rounded f32 sqrt (Figueroa: f64 sqrt then round == RN f32 sqrt).
__device__ __forceinline__ float sqrt_f32_exact(float s) {
  return (float)sqrt((double)s);
}

// v / max(||v||, 1e-12) in f32, numpy op order: ((x*x + y*y) + z*z)
__device__ __forceinline__ void norm3f(float& x, float& y, float& z) {
  float s = (x*x + y*y) + z*z;
  float n = sqrt_f32_exact(s);
  n = fmaxf(n, 1e-12f);
  x = x / n; y = y / n; z = z / n;
}

// Blocks 0..16:  peW[rel+32][h] = b_edge[h] + sum_j pe_j(rel)*W_pe[j][h]  (65x64 f32)
// Blocks 17..32: allc[res][0..14] = 5 atoms (N,CA,C,O,virtualCB), row padded to 16 floats
__global__ __launch_bounds__(256) void prep_kernel(
    const float* __restrict__ coords,   // (B,L,4,3) f32
    const float* __restrict__ W_edge,   // (989,64) f32
    const float* __restrict__ b_edge,   // (64,) f32
    float*       __restrict__ peW,      // (65,64) f32
    float*       __restrict__ allc)     // (NRES,16) f32
{
  const int t = threadIdx.x;
  if (blockIdx.x < 17) {
    __shared__ double pe[4][64];
    const int row = t >> 6;                 // 0..3
    const int r   = blockIdx.x * 4 + row;   // rel+32 in [0,65)
    const int h   = t & 63;
    if (r < 65 && h < 32) {
      const double c = -log(10000.0) / 64.0;
      const double ang = (double)(r - 32) * exp((double)(2 * h) * c);
      pe[row][2*h]     = sin(ang);
      pe[row][2*h + 1] = cos(ang);
    }
    __syncthreads();
    if (r < 65) {
      double acc = (double)b_edge[h];
      for (int j = 0; j < 64; ++j)
        acc += pe[row][j] * (double)W_edge[(WD_ROWS + j) * H_ + h];
      peW[r * H_ + h] = (float)acc;
    }
  } else {
    const int res = (blockIdx.x - 17) * 256 + t;   // 0..NRES-1
    if (res >= NRES) return;
    const float* cp = coords + (size_t)res * 12;
    float a[4][3];
    #pragma unroll
    for (int q = 0; q < 4; ++q)
      #pragma unroll
      for (int d = 0; d < 3; ++d)
        a[q][d] = cp[q * 3 + d];

    // ca_n = normalize(N - CA); ca_c = normalize(C - CA)   (f32, numpy order)
    float nx = a[0][0]-a[1][0], ny = a[0][1]-a[1][1], nz = a[0][2]-a[1][2];
    float cx = a[2][0]-a[1][0], cy = a[2][1]-a[1][1], cz = a[2][2]-a[1][2];
    norm3f(nx, ny, nz);
    norm3f(cx, cy, cz);
    float bx = nx + cx, by = ny + cy, bz = nz + cz;          // bisector
    norm3f(bx, by, bz);
    float px = ny*cz - nz*cy, py = nz*cx - nx*cz, pz = nx*cy - ny*cx;  // perp
    norm3f(px, py, pz);
    float dx = -bx + 0.5f*px, dy = -by + 0.5f*py, dz = -bz + 0.5f*pz;  // cb_dir
    norm3f(dx, dy, dz);

    float row[16];
    #pragma unroll
    for (int q = 0; q < 4; ++q)
      #pragma unroll
      for (int d = 0; d < 3; ++d)
        row[q * 3 + d] = a[q][d];
    row[12] = a[1][0] + 1.54f * dx;
    row[13] = a[1][1] + 1.54f * dy;
    row[14] = a[1][2] + 1.54f * dz;
    row[15] = 0.0f;

    float4* o = (float4*)(allc + (size_t)res * 16);
    o[0] = make_float4(row[0],  row[1],  row[2],  row[3]);
    o[1] = make_float4(row[4],  row[5],  row[6],  row[7]);
    o[2] = make_float4(row[8],  row[9],  row[10], row[11]);
    o[3] = make_float4(row[12], row[13], row[14], row[15]);
  }
}

// One block = one (b,l) center with its K=32 neighbors.
__global__ __launch_bounds__(256) void edge_kernel(
    const int*   __restrict__ nbr,      // (B,L,K) int32
    const float* __restrict__ allc,     // (NRES,16) f32
    const float* __restrict__ W_edge,   // (989,64) f32
    const float* __restrict__ peW,      // (65,64) f32
    float*       __restrict__ out)      // (B,L,K,64) f32
{
  __shared__ float          center[16];
  __shared__ float          natoms[K_][16];
  __shared__ unsigned short fidx[K_][25];
  __shared__ int            relid[K_];

  const int t   = threadIdx.x;
  const int bl  = blockIdx.x;           // b*L_ + l
  const int l   = bl & (L_ - 1);
  const int g0  = bl * K_;

  if (t < 4) {
    ((float4*)center)[t] = ((const float4*)(allc + (size_t)bl * 16))[t];
  }
  if (t < 4 * K_) {
    const int i = t >> 2, c = t & 3;
    const int nb = nbr[g0 + i];
    const int brow = (bl & ~(L_ - 1)) + nb;   // b*L_ + nb
    ((float4*)natoms[i])[c] = ((const float4*)(allc + (size_t)brow * 16))[c];
    if (c == 0) {
      int rel = nb - l;
      rel = rel < -32 ? -32 : (rel > 32 ? 32 : rel);
      relid[i] = rel + 32;
    }
  }
  __syncthreads();

  // 25 pair distances per item -> exact f32 searchsorted
  for (int task = t; task < K_ * 25; task += 256) {
    const int i  = task / 25;
    const int p  = task - i * 25;
    const int a1 = p / 5, a2 = p - a1 * 5;
    const float dx = center[a1 * 3 + 0] - natoms[i][a2 * 3 + 0];
    const float dy = center[a1 * 3 + 1] - natoms[i][a2 * 3 + 1];
    const float dz = center[a1 * 3 + 2] - natoms[i][a2 * 3 + 2];
    const float d2 = (dx*dx + dy*dy) + dz*dz;   // numpy add.reduce order
    const float d  = sqrt_f32_exact(d2);
    int m = (int)ceilf((d - 2.0f) * 2.0f);      // seed; fixups make it exact
    if (m < 0)  m = 0;
    if (m > NBINS) m = NBINS;
    while (m < NBINS && (2.0f + 0.5f * (float)m) < d) ++m;
    while (m > 0 && !((2.0f + 0.5f * (float)(m - 1)) < d)) --m;
    const int idx = m < (NBINS - 1) ? m : (NBINS - 1);
    fidx[i][p] = (unsigned short)(p * NBINS + idx);
  }
  __syncthreads();

  // out[g][h] = peW[rel] + sum_p W_dist[fidx[p]]   (8 h per thread)
  {
    const int i  = t >> 3;
    const int hq = (t & 7) * 8;
    const int g  = g0 + i;

    const float4* pw = (const float4*)(peW + relid[i] * H_ + hq);
    const float4 p0 = pw[0], p1 = pw[1];
    float acc[8] = {p0.x, p0.y, p0.z, p0.w, p1.x, p1.y, p1.z, p1.w};

    #pragma unroll 5
    for (int p = 0; p < 25; ++p) {
      const int f = fidx[i][p];
      const float4* wr = (const float4*)(W_edge + (size_t)f * H_ + hq);
      const float4 w0 = wr[0], w1 = wr[1];
      acc[0] += w0.x; acc[1] += w0.y; acc[2] += w0.z; acc[3] += w0.w;
      acc[4] += w1.x; acc[5] += w1.y; acc[6] += w1.z; acc[7] += w1.w;
    }

    float4* po = (float4*)(out + (size_t)g * H_ + hq);
    po[0] = make_float4(acc[0], acc[1], acc[2], acc[3]);
    po[1] = make_float4(acc[4], acc[5], acc[6], acc[7]);
  }
}

extern "C" void kernel_launch(void* const* d_in, const int* in_sizes, int n_in,
                              void* d_out, int out_size, void* d_ws, size_t ws_size,
                              hipStream_t stream) {
  const float* coords = (const float*)d_in[0];
  const int*   nbr    = (const int*)d_in[1];
  const float* W      = (const float*)d_in[2];
  const float* bvec   = (const float*)d_in[3];
  float*       out    = (float*)d_out;
  float*       peW    = (float*)d_ws;                       // 65*64*4   = 16.6 KB
  float*       allc   = (float*)((char*)d_ws + 32768);      // 4096*16*4 = 262 KB

  prep_kernel<<<33, 256, 0, stream>>>(coords, W, bvec, peW, allc);
  edge_kernel<<<NRES, 256, 0, stream>>>(nbr, allc, W, peW, out);
}